// Round 8
// baseline (224.533 us; speedup 1.0000x reference)
//
#include <hip/hip_runtime.h>
#include <hip/hip_bf16.h>
#include <stdint.h>

typedef __bf16 bf16_t;
typedef __attribute__((ext_vector_type(8))) __bf16 bf16x8;
typedef __attribute__((ext_vector_type(4))) __bf16 bf16x4;
typedef __attribute__((ext_vector_type(4))) float f32x4;

static constexpr int T_SEQ = 2048;
static constexpr int HID   = 2048;
static constexpr int NHEAD = 32;
static constexpr int NKVH  = 8;
static constexpr int HDIM  = 64;
static constexpr int QKVD  = 3072;   // 64*(32+16)

__device__ inline f32x4 mfma16(bf16x8 a, bf16x8 b, f32x4 c) {
    return __builtin_amdgcn_mfma_f32_16x16x32_bf16(a, b, c, 0, 0, 0);
}

__device__ inline void load_lds16(const bf16_t* g, bf16_t* l) {
    __builtin_amdgcn_global_load_lds(
        (const __attribute__((address_space(1))) void*)g,
        (__attribute__((address_space(3))) void*)l, 16, 0, 0);
}

// ---------------- prep: weight transposes + RMSNorm (one dispatch) ----------------
__global__ __launch_bounds__(256) void prep_kernel(const float* __restrict__ Wq,
                                                   const float* __restrict__ Wo,
                                                   bf16_t* __restrict__ Tq,
                                                   bf16_t* __restrict__ To,
                                                   const float* __restrict__ x,
                                                   const float* __restrict__ scale,
                                                   bf16_t* __restrict__ normed) {
    __shared__ float tile[64 * 65];
    int b = blockIdx.x;
    const int t = threadIdx.x;
    if (b < 2560) {
        const float* in; bf16_t* outw; int NN, KK, bx, by;
        if (b < 1536) { in = Wq; outw = Tq; NN = QKVD; KK = HID; bx = b % 48; by = b / 48; }
        else { b -= 1536; in = Wo; outw = To; NN = HID; KK = HID; bx = b % 32; by = b / 32; }
        const int c4 = (t & 15) * 4;
#pragma unroll
        for (int i = 0; i < 4; ++i) {
            int r = (t >> 4) + i * 16;
            float4 v = *(const float4*)(in + (size_t)(by*64 + r) * NN + bx*64 + c4);
            tile[r*65 + c4 + 0] = v.x; tile[r*65 + c4 + 1] = v.y;
            tile[r*65 + c4 + 2] = v.z; tile[r*65 + c4 + 3] = v.w;
        }
        __syncthreads();
        const int kc = t & 7;
#pragma unroll
        for (int i = 0; i < 2; ++i) {
            int n = (t >> 3) + i * 32;
            bf16x8 o;
#pragma unroll
            for (int j = 0; j < 8; ++j) o[j] = (bf16_t)tile[(kc*8 + j)*65 + n];
            *(bf16x8*)(outw + (size_t)(bx*64 + n) * KK + by*64 + kc*8) = o;
        }
    } else {
        int row = b - 2560;
        const float4* x4 = (const float4*)(x + (size_t)row * HID);
        const float4* s4 = (const float4*)scale;
        float4 v0 = x4[t], v1 = x4[t + 256];
        float ss = v0.x*v0.x + v0.y*v0.y + v0.z*v0.z + v0.w*v0.w
                 + v1.x*v1.x + v1.y*v1.y + v1.z*v1.z + v1.w*v1.w;
#pragma unroll
        for (int off = 32; off > 0; off >>= 1) ss += __shfl_down(ss, off);
        if ((t & 63) == 0) tile[t >> 6] = ss;
        __syncthreads();
        float total = tile[0] + tile[1] + tile[2] + tile[3];
        float inv = rsqrtf(total * (1.0f / HID) + 1e-5f);
        float4 sc0 = s4[t], sc1 = s4[t + 256];
        bf16_t* outr = normed + (size_t)row * HID;
        bf16x4 o0, o1;
        o0.x = (bf16_t)(v0.x*inv*sc0.x); o0.y = (bf16_t)(v0.y*inv*sc0.y);
        o0.z = (bf16_t)(v0.z*inv*sc0.z); o0.w = (bf16_t)(v0.w*inv*sc0.w);
        o1.x = (bf16_t)(v1.x*inv*sc1.x); o1.y = (bf16_t)(v1.y*inv*sc1.y);
        o1.z = (bf16_t)(v1.z*inv*sc1.z); o1.w = (bf16_t)(v1.w*inv*sc1.w);
        *(bf16x4*)(outr + 4*t)        = o0;
        *(bf16x4*)(outr + 1024 + 4*t) = o1;
    }
}

// ---------------- split-K GEMM, 128x128 tile, BK=64 (round-6 verified core) ----------
// K-split count = gridDim.z (kh = K/gridDim.z must be a multiple of 64).
// Each 32-k sub-tile uses the round-2 verified conflict-free geometry.
__global__ __launch_bounds__(256) void gemm_splitk(const bf16_t* __restrict__ A,
                                                   const bf16_t* __restrict__ Bt,
                                                   bf16_t* __restrict__ Cpart,
                                                   int M, int N, int K) {
    __shared__ __align__(16) bf16_t Asm[2 * 128 * 32];   // 16 KB
    __shared__ __align__(16) bf16_t Bsm[2 * 128 * 32];   // 16 KB
    const int tid = threadIdx.x;
    const int bm = blockIdx.y * 128, bn = blockIdx.x * 128;
    const int kh = K / gridDim.z;
    const int kb = blockIdx.z * kh;
    const int lane = tid & 63, wave = tid >> 6;
    const int wm = (wave & 1) * 64, wn = (wave >> 1) * 64;
    const int lm = lane & 15, quad = lane >> 4;

    f32x4 acc[4][4];
#pragma unroll
    for (int i = 0; i < 4; ++i)
#pragma unroll
        for (int j = 0; j < 4; ++j) acc[i][j] = (f32x4){0.f, 0.f, 0.f, 0.f};

    const int cid0 = tid, cid1 = tid + 256;
    const int r0 = cid0 >> 2, c0 = (cid0 & 3) ^ ((r0 >> 1) & 3);
    const int r1 = cid1 >> 2, c1 = (cid1 & 3) ^ ((r1 >> 1) & 3);
    const bf16_t* Ab = A  + (size_t)bm * K + kb;
    const bf16_t* Bb = Bt + (size_t)bn * K + kb;
    const size_t ga0 = (size_t)r0 * K + c0 * 8;
    const size_t ga1 = (size_t)r1 * K + c1 * 8;
    bf16_t* ldsA0a = &Asm[wave * 512];
    bf16_t* ldsA0b = &Asm[2048 + wave * 512];
    bf16_t* ldsA1a = &Asm[4096 + wave * 512];
    bf16_t* ldsA1b = &Asm[4096 + 2048 + wave * 512];
    bf16_t* ldsB0a = &Bsm[wave * 512];
    bf16_t* ldsB0b = &Bsm[2048 + wave * 512];
    bf16_t* ldsB1a = &Bsm[4096 + wave * 512];
    bf16_t* ldsB1b = &Bsm[4096 + 2048 + wave * 512];
    const int swz = (quad ^ ((lm >> 1) & 3)) * 8;

    for (int k0 = 0; k0 < kh; k0 += 64) {
        load_lds16(Ab + ga0 + k0,      ldsA0a);
        load_lds16(Ab + ga1 + k0,      ldsA0b);
        load_lds16(Ab + ga0 + k0 + 32, ldsA1a);
        load_lds16(Ab + ga1 + k0 + 32, ldsA1b);
        load_lds16(Bb + ga0 + k0,      ldsB0a);
        load_lds16(Bb + ga1 + k0,      ldsB0b);
        load_lds16(Bb + ga0 + k0 + 32, ldsB1a);
        load_lds16(Bb + ga1 + k0 + 32, ldsB1b);
        __syncthreads();
#pragma unroll
        for (int ks = 0; ks < 2; ++ks) {
            bf16x8 af[4], bfr[4];
#pragma unroll
            for (int i = 0; i < 4; ++i)
                af[i]  = *(const bf16x8*)&Asm[ks*4096 + (wm + i*16 + lm)*32 + swz];
#pragma unroll
            for (int j = 0; j < 4; ++j)
                bfr[j] = *(const bf16x8*)&Bsm[ks*4096 + (wn + j*16 + lm)*32 + swz];
#pragma unroll
            for (int i = 0; i < 4; ++i)
#pragma unroll
                for (int j = 0; j < 4; ++j) acc[i][j] = mfma16(af[i], bfr[j], acc[i][j]);
        }
        __syncthreads();
    }

    bf16_t* Cp = Cpart + (size_t)blockIdx.z * M * N;
#pragma unroll
    for (int i = 0; i < 4; ++i) {
        int gr = bm + wm + i*16 + quad*4;
#pragma unroll
        for (int j = 0; j < 4; ++j) {
            int gc = bn + wn + j*16 + lm;
#pragma unroll
            for (int r = 0; r < 4; ++r)
                Cp[(size_t)(gr + r)*N + gc] = (bf16_t)acc[i][j][r];
        }
    }
}

// ---------------- combine partials + bias + rope (vectorized), scatter to Q/K/V ----------
__global__ __launch_bounds__(192) void rope_split(const bf16_t* __restrict__ qp0,
                                                  const bf16_t* __restrict__ qp1,
                                                  const float* __restrict__ qbias,
                                                  const float* __restrict__ cost,
                                                  const float* __restrict__ sint,
                                                  bf16_t* __restrict__ Qb,
                                                  bf16_t* __restrict__ Kb,
                                                  bf16_t* __restrict__ Vb) {
    const int t = blockIdx.x;
    const int hr = threadIdx.x >> 2, p0 = (threadIdx.x & 3) * 8;
    const bf16_t* r0 = qp0 + (size_t)t * QKVD + hr * 64;
    const bf16_t* r1 = qp1 + (size_t)t * QKVD + hr * 64;
    bf16x8 a1 = *(const bf16x8*)(r0 + p0);
    bf16x8 a2 = *(const bf16x8*)(r0 + p0 + 32);
    bf16x8 b1 = *(const bf16x8*)(r1 + p0);
    bf16x8 b2 = *(const bf16x8*)(r1 + p0 + 32);
    const float* qb = qbias + hr * 64;
    float x1[8], x2[8];
#pragma unroll
    for (int j = 0; j < 8; ++j) {
        x1[j] = (float)a1[j] + (float)b1[j] + qb[p0 + j];
        x2[j] = (float)a2[j] + (float)b2[j] + qb[p0 + j + 32];
    }
    bf16x8 w1, w2;
    if (hr < 40) {
        const float* c = cost + (size_t)t * 32 + p0;
        const float* s = sint + (size_t)t * 32 + p0;
#pragma unroll
        for (int j = 0; j < 8; ++j) {
            float cc = c[j], ss = s[j];
            w1[j] = (bf16_t)(x1[j]*cc - x2[j]*ss);
            w2[j] = (bf16_t)(x2[j]*cc + x1[j]*ss);
        }
    } else {
#pragma unroll
        for (int j = 0; j < 8; ++j) { w1[j] = (bf16_t)x1[j]; w2[j] = (bf16_t)x2[j]; }
    }
    bf16_t* dst;
    if (hr < 32)      dst = Qb + ((size_t)t*NHEAD + hr)      * HDIM;
    else if (hr < 40) dst = Kb + ((size_t)t*NKVH + (hr-32))  * HDIM;
    else              dst = Vb + ((size_t)t*NKVH + (hr-40))  * HDIM;
    *(bf16x8*)(dst + p0)      = w1;
    *(bf16x8*)(dst + p0 + 32) = w2;
}

// ---------------- combine 4 out-proj partials + bias + residual (bf16x8 one-pass) --------
__global__ __launch_bounds__(256) void combine_out4(const bf16_t* __restrict__ p,
                                                    const float* __restrict__ bias,
                                                    const float* __restrict__ x,
                                                    float* __restrict__ out) {
    const size_t SL = (size_t)T_SEQ * HID;
    size_t i8 = ((size_t)blockIdx.x * 256 + threadIdx.x) * 8;   // grid covers T*HID/8
    bf16x8 a0 = *(const bf16x8*)(p + i8);
    bf16x8 a1 = *(const bf16x8*)(p + SL + i8);
    bf16x8 a2 = *(const bf16x8*)(p + 2*SL + i8);
    bf16x8 a3 = *(const bf16x8*)(p + 3*SL + i8);
    int col = (int)(i8 & (HID - 1));
    const float* bi = bias + col;
    const float* xv = x + i8;
    float* ov = out + i8;
#pragma unroll
    for (int j = 0; j < 8; ++j)
        ov[j] = (float)a0[j] + (float)a1[j] + (float)a2[j] + (float)a3[j] + bi[j] + xv[j];
}

// ---------------- attention: direct global Q/K frags, one barrier, conflict-free Vt ------
__global__ __launch_bounds__(256) void attn_kernel(const bf16_t* __restrict__ Qb,
                                                   const bf16_t* __restrict__ Kb,
                                                   const bf16_t* __restrict__ Vb,
                                                   const float* __restrict__ sinks,
                                                   bf16_t* __restrict__ attnb) {
    __shared__ __align__(16) bf16_t Vt[64 * 200];
    __shared__ __align__(16) bf16_t Ws[64 * 200];

    const int tid = threadIdx.x;
    const int qt = blockIdx.x, h = blockIdx.y;
    const int qs = qt * 64;
    const int nkv = h >> 2;

    {
        const int off = (tid >> 5) * 8;
#pragma unroll
        for (int it = 0; it < 3; ++it) {
            int j2 = (tid & 31) + 32 * it;
            int kg0 = qs - 128 + 2*j2;     if (kg0 < 0) kg0 = 0;
            int kg1 = qs - 128 + 2*j2 + 1; if (kg1 < 0) kg1 = 0;
            union { uint4 u; bf16_t e[8]; } v0, v1;
            v0.u = *(const uint4*)(Vb + ((size_t)kg0*NKVH + nkv)*HDIM + off);
            v1.u = *(const uint4*)(Vb + ((size_t)kg1*NKVH + nkv)*HDIM + off);
#pragma unroll
            for (int r = 0; r < 8; ++r) {
                union { uint u; bf16_t e[2]; } pp;
                pp.e[0] = v0.e[r]; pp.e[1] = v1.e[r];
                *(uint*)&Vt[(off + r)*200 + 2*j2] = pp.u;
            }
        }
    }

    const int lane = tid & 63, wave = tid >> 6;
    const int lm = lane & 15, quad = lane >> 4;
    const int w16 = wave * 16;

    f32x4 S[12];
#pragma unroll
    for (int jt = 0; jt < 12; ++jt) S[jt] = (f32x4){0.f, 0.f, 0.f, 0.f};
    const bf16_t* Qrow = Qb + ((size_t)(qs + w16 + lm)*NHEAD + h)*HDIM + quad*8;
    int krow[12];
#pragma unroll
    for (int jt = 0; jt < 12; ++jt) {
        int kg = qs - 128 + jt*16 + lm;
        krow[jt] = kg < 0 ? 0 : kg;
    }
#pragma unroll
    for (int ks = 0; ks < 2; ++ks) {
        bf16x8 aq = *(const bf16x8*)(Qrow + ks*32);
#pragma unroll
        for (int jt = 0; jt < 12; ++jt) {
            bf16x8 bk = *(const bf16x8*)(Kb + ((size_t)krow[jt]*NKVH + nkv)*HDIM + ks*32 + quad*8);
            S[jt] = mfma16(aq, bk, S[jt]);
        }
    }

    const float sink = sinks[h];
#pragma unroll
    for (int reg = 0; reg < 4; ++reg) {
        const int qg = qs + w16 + quad*4 + reg;
        float mx = -1e30f;
#pragma unroll
        for (int jt = 0; jt < 12; ++jt) {
            int kg = qs - 128 + jt*16 + lm;
            float sv = S[jt][reg] * 0.125f;
            bool valid = (kg >= 0) && (kg <= qg) && (qg - kg <= 128);
            sv = valid ? sv : -1e30f;
            S[jt][reg] = sv;
            mx = fmaxf(mx, sv);
        }
#pragma unroll
        for (int off = 1; off < 16; off <<= 1) mx = fmaxf(mx, __shfl_xor(mx, off));
        float M = fmaxf(mx, sink);
        float sum = 0.f;
#pragma unroll
        for (int jt = 0; jt < 12; ++jt) {
            float e = __expf(S[jt][reg] - M);
            S[jt][reg] = e; sum += e;
        }
#pragma unroll
        for (int off = 1; off < 16; off <<= 1) sum += __shfl_xor(sum, off);
        float rden = 1.f / (sum + __expf(sink - M));
#pragma unroll
        for (int jt = 0; jt < 12; ++jt)
            Ws[(w16 + quad*4 + reg)*200 + jt*16 + lm] = (bf16_t)(S[jt][reg] * rden);
    }
    __syncthreads();

    f32x4 O[4];
#pragma unroll
    for (int nt = 0; nt < 4; ++nt) O[nt] = (f32x4){0.f, 0.f, 0.f, 0.f};
#pragma unroll
    for (int ks = 0; ks < 6; ++ks) {
        bf16x8 aw = *(const bf16x8*)&Ws[(w16 + lm)*200 + ks*32 + quad*8];
#pragma unroll
        for (int nt = 0; nt < 4; ++nt) {
            bf16x8 bv = *(const bf16x8*)&Vt[(nt*16 + lm)*200 + ks*32 + quad*8];
            O[nt] = mfma16(aw, bv, O[nt]);
        }
    }
#pragma unroll
    for (int nt = 0; nt < 4; ++nt)
#pragma unroll
        for (int reg = 0; reg < 4; ++reg)
            attnb[(size_t)(qs + w16 + quad*4 + reg)*HID + h*HDIM + nt*16 + lm] =
                (bf16_t)(O[nt][reg]);
}

// ---------------- launch ----------------
extern "C" void kernel_launch(void* const* d_in, const int* in_sizes, int n_in,
                              void* d_out, int out_size, void* d_ws, size_t ws_size,
                              hipStream_t stream) {
    (void)in_sizes; (void)n_in; (void)out_size; (void)ws_size;
    const float* x          = (const float*)d_in[0];
    const float* scale      = (const float*)d_in[1];
    const float* sinks      = (const float*)d_in[2];
    const float* qkv_kernel = (const float*)d_in[3];
    const float* qkv_bias   = (const float*)d_in[4];
    const float* out_kernel = (const float*)d_in[5];
    const float* out_bias   = (const float*)d_in[6];
    const float* cos_t      = (const float*)d_in[7];
    const float* sin_t      = (const float*)d_in[8];
    float* out = (float*)d_out;

    // ws plan (64 MiB, aliasing by liveness):
    //   [ 0, 8)   Wt_out  bf16 [2048][2048]  (alive until out gemm)
    //   [ 8,20)   Wt_qkv  bf16 [3072][2048]  (dead after QKV gemm)
    //   [ 8,16)   attnb   bf16 [T][2048]     (aliases Wt_qkv; written by attn)
    //   [20,28)   normed  bf16 [T][2048]     (dead after QKV gemm)
    //   [28,52)   qkvp    bf16 [2][T][3072]  (dead after rope)
    //   [20,52)   outp    bf16 [4][T][2048]  (aliases normed+qkvp; written by out gemm)
    //   [52,64)   Qb/Kb/Vb bf16
    char* ws = (char*)d_ws;
    const size_t MiB = 1048576;
    bf16_t* Wt_out = (bf16_t*)(ws);
    bf16_t* Wt_qkv = (bf16_t*)(ws + 8*MiB);
    bf16_t* attnb  = (bf16_t*)(ws + 8*MiB);
    bf16_t* normed = (bf16_t*)(ws + 20*MiB);
    bf16_t* qkvp   = (bf16_t*)(ws + 28*MiB);
    bf16_t* outp   = (bf16_t*)(ws + 20*MiB);
    bf16_t* Qb     = (bf16_t*)(ws + 52*MiB);
    bf16_t* Kb     = (bf16_t*)(ws + 60*MiB);
    bf16_t* Vb     = (bf16_t*)(ws + 62*MiB);

    prep_kernel<<<4608, 256, 0, stream>>>(qkv_kernel, out_kernel, Wt_qkv, Wt_out,
                                          x, scale, normed);
    gemm_splitk<<<dim3(QKVD/128, T_SEQ/128, 2), 256, 0, stream>>>(normed, Wt_qkv, qkvp,
                                                                  T_SEQ, QKVD, HID);
    rope_split<<<T_SEQ, 192, 0, stream>>>(qkvp, qkvp + (size_t)T_SEQ*QKVD, qkv_bias,
                                          cos_t, sin_t, Qb, Kb, Vb);
    attn_kernel<<<dim3(T_SEQ/64, NHEAD), 256, 0, stream>>>(Qb, Kb, Vb, sinks, attnb);
    gemm_splitk<<<dim3(HID/128, T_SEQ/128, 4), 256, 0, stream>>>(attnb, Wt_out, outp,
                                                                 T_SEQ, HID, HID);
    combine_out4<<<(T_SEQ*HID/8)/256, 256, 0, stream>>>(outp, out_bias, x, out);
}